// Round 6
// baseline (486.290 us; speedup 1.0000x reference)
//
#include <hip/hip_runtime.h>
#include <hip/hip_bf16.h>

#define NPTS 500000
#define NGR  64
#define TR   256
#define NT2  ((NPTS + TR - 1) / TR)   // 1954
#define GRID2 512

typedef __bf16 bf16x8 __attribute__((ext_vector_type(8)));
typedef float f32x4 __attribute__((ext_vector_type(4)));
typedef unsigned int u32x4 __attribute__((ext_vector_type(4)));

// ---- workspace layout (bytes), all 16B aligned ----
#define OFF_DONE   4096     // u32      : completion counter (k_out fused into k_main tail)
#define OFF_OUTACC 6144     // u32[8192]: order-preserving max accum
#define OFF_CBIAS  38912    // f32[8192]: per-graph GEMM1 bias row
#define OFF_W1AT   73728    // u16[8192] : bf16 W1[64:128]^T [n=128][k=64]   (plain layout)
#define OFF_W2T    90112    // u16[16384]: bf16 W2^T [n=128][k=128]          (plain layout)
#define OFF_W1ET   122880   // u16[4096] : bf16 W1[128:131]^T pad [n=128][k=32] (plain)

// order-preserving float->u32 map (max over u32 == max over float)
__device__ __forceinline__ unsigned mapf(float f) {
    union { float f; unsigned u; } v; v.f = f;
    return ((int)v.u >= 0) ? (v.u | 0x80000000u) : ~v.u;
}

// ---- fused pre-pass (one 1024-thread block per graph):
//      distributed prep (W transposes, outacc/done init) +
//      COM (fp64) + argmin (truncated key) + cbias. No atomics. ----
__global__ __launch_bounds__(1024) void k_pre(
                      const float* __restrict__ pos,
                      const int* __restrict__ batch,
                      const float* __restrict__ x,
                      const float* __restrict__ W1,
                      const float* __restrict__ b1,
                      const float* __restrict__ W2,
                      const float* __restrict__ lfr,
                      unsigned short* __restrict__ W1aT,
                      unsigned short* __restrict__ W2T,
                      unsigned short* __restrict__ W1eT,
                      unsigned* __restrict__ outacc,
                      unsigned* __restrict__ done,
                      float* __restrict__ cbias,
                      float* __restrict__ outf) {
    __shared__ double sd[16][3];
    __shared__ unsigned long long sk[16];
    __shared__ double scom[3];
    __shared__ int sid;
    __shared__ float sposd[3];
    __shared__ float sp[4][128];
    __shared__ int sse[2];

    int g = blockIdx.x, t = threadIdx.x;
    int lane = t & 63, wv = t >> 6;   // wv 0..15

    // ---- distributed prep: 64*1024 = 65536 threads cover all items ----
    {
        int i = g * 1024 + t;
        if (i == 0) *done = 0u;
        if (i < 8192) {
            outacc[i] = 0u;
            int n = i >> 6, k = i & 63;
            W1aT[i] = (unsigned short)(__builtin_bit_cast(unsigned, (float)(__bf16)W1[(64 + k) * 128 + n]) >> 16);
        } else if (i < 8192 + 16384) {
            int j = i - 8192; int n = j >> 7, k = j & 127;
            W2T[j] = (unsigned short)(__builtin_bit_cast(unsigned, (float)(__bf16)W2[k * 128 + n]) >> 16);
        } else if (i < 8192 + 16384 + 4096) {
            int j = i - 24576; int n = j >> 5, k = j & 31;
            unsigned short v = 0;
            if (k < 3) v = (unsigned short)(__builtin_bit_cast(unsigned, (float)(__bf16)W1[(128 + k) * 128 + n]) >> 16);
            W1eT[j] = v;
        }
    }

    // ---- own-range binary search (batch is sorted) ----
    if (t < 2) {
        int target = g + t;
        int lo = 0, hi = NPTS;
        while (lo < hi) {
            int mid = (lo + hi) >> 1;
            if (batch[mid] < target) lo = mid + 1; else hi = mid;
        }
        sse[t] = lo;
    }
    __syncthreads();
    int s = sse[0], e = sse[1];

    // pass 1: fp64 position sums
    double sx = 0.0, sy = 0.0, sz = 0.0;
    for (int i = s + t; i < e; i += 1024) {
        sx += (double)pos[i * 3 + 0];
        sy += (double)pos[i * 3 + 1];
        sz += (double)pos[i * 3 + 2];
    }
    #pragma unroll
    for (int m = 1; m < 64; m <<= 1) {
        sx += __shfl_xor(sx, m);
        sy += __shfl_xor(sy, m);
        sz += __shfl_xor(sz, m);
    }
    if (lane == 0) { sd[wv][0] = sx; sd[wv][1] = sy; sd[wv][2] = sz; }
    __syncthreads();
    if (t == 0) {
        double ax = 0.0, ay = 0.0, az = 0.0;
        for (int q = 0; q < 16; ++q) { ax += sd[q][0]; ay += sd[q][1]; az += sd[q][2]; }
        double cnt = (double)(e - s);
        double rc = 1.0 / (cnt > 1.0 ? cnt : 1.0);
        scom[0] = ax * rc; scom[1] = ay * rc; scom[2] = az * rc;
    }
    __syncthreads();
    double cx = scom[0], cy = scom[1], cz = scom[2];

    // pass 2: argmin of fp64 d2, key = (trunc d2-bits) | id
    unsigned long long key = ~0ULL;
    for (int i = s + t; i < e; i += 1024) {
        double dx = (double)pos[i * 3 + 0] - cx;
        double dy = (double)pos[i * 3 + 1] - cy;
        double dz = (double)pos[i * 3 + 2] - cz;
        double d2 = __builtin_fma(dx, dx, __builtin_fma(dy, dy, dz * dz));
        unsigned long long b = __builtin_bit_cast(unsigned long long, d2);
        unsigned long long k2 = (b & ~0xFFFFFULL) | (unsigned long long)i;
        key = k2 < key ? k2 : key;
    }
    #pragma unroll
    for (int m = 1; m < 64; m <<= 1) {
        unsigned long long o = __shfl_xor(key, m);
        key = o < key ? o : key;
    }
    if (lane == 0) sk[wv] = key;
    __syncthreads();
    if (t == 0) {
        unsigned long long k = sk[0];
        for (int q = 1; q < 16; ++q) if (sk[q] < k) k = sk[q];
        int id = (int)(k & 0xFFFFFULL);
        if (id > NPTS - 1) id = NPTS - 1;
        sid = id;
    }
    __syncthreads();
    int id = sid;

    if (t < 3) {
        float p = pos[id * 3 + t];
        sposd[t] = p;
        outf[8192 + g * 3 + t] = p;
    }
    if (t == 4) outf[8192 + 192 + g] = (float)batch[id];
    if (t < 9) outf[8192 + 256 + g * 9 + t] = lfr[id * 9 + t];

    // cbias: 4-way split over k, then ordered combine
    if (t < 512) {
        int c = t & 127, p = t >> 7;
        float part = 0.f;
        #pragma unroll
        for (int kq = 0; kq < 16; ++kq) {
            int k = p * 16 + kq;
            float xd = x[id * 64 + k];
            part += xd * (W1[k * 128 + c] - W1[(64 + k) * 128 + c]);
        }
        sp[p][c] = part;
    }
    __syncthreads();
    if (t < 128) {
        int c = t;
        float sv = b1[c] + sp[0][c] + sp[1][c] + sp[2][c] + sp[3][c];
        sv -= sposd[0] * W1[128 * 128 + c] + sposd[1] * W1[129 * 128 + c] + sposd[2] * W1[130 * 128 + c];
        cbias[g * 128 + c] = sv;
    }
}

// ---- main: round-1 structure (8 waves x 32 rows, 512 thr, (512,2) -> 128-VGPR
//      cap, which r1 fit cleanly at 108) with ONE structural change: W tables
//      read from global (L1/L2-hot) so LDS holds only h stripes (69632 B) and
//      the HW fits 2 blocks/CU = 4 waves/SIMD. Register headroom engineered:
//      no bfrE table (W1e loaded per-t8), no cb0 preload (cbias read in
//      epilogue, outside GEMM1 live range), rowv folded into rowg=-1. ----
__global__ __launch_bounds__(512, 2) void k_main(
    const float* __restrict__ x,
    const float* __restrict__ pos,
    const int* __restrict__ batch,
    const unsigned short* __restrict__ W1aT,
    const unsigned short* __restrict__ W2T,
    const unsigned short* __restrict__ W1eT,
    const float* __restrict__ cbias,
    unsigned* __restrict__ outacc,
    unsigned* __restrict__ done,
    const float* __restrict__ b2v,
    float* __restrict__ outf)
{
    // h stripes only: 8 waves x [32][136] bf16 (8704 B each) = 69632 B
    __shared__ alignas(16) unsigned char smem[69632];
    __shared__ unsigned sflag;

    const int tid  = threadIdx.x;        // 0..511
    const int w    = tid >> 6;           // 0..7
    const int lane = tid & 63;
    const int quad = lane >> 4;
    const int mr   = lane & 15;

    __bf16* hsb = (__bf16*)smem + w * 4352;   // [32][136]
    const unsigned short* hss = (const unsigned short*)hsb;

    for (int t = blockIdx.x; t < NT2; t += GRID2) {
        const int row0 = t * TR + 32 * w;   // this wave's 32 global rows

        // ---- A loads, direct global (issued first, 8x dwordx4) ----
        f32x4 av[2][4];
        #pragma unroll
        for (int u = 0; u < 2; ++u) {
            int gr2 = row0 + 16 * u + mr; if (gr2 > NPTS - 1) gr2 = NPTS - 1;
            const float* xp = x + (size_t)gr2 * 64 + quad * 8;
            av[u][0] = *(const f32x4*)(xp);
            av[u][1] = *(const f32x4*)(xp + 4);
            av[u][2] = *(const f32x4*)(xp + 32);
            av[u][3] = *(const f32x4*)(xp + 36);
        }

        // ---- per-tile meta (overlaps A-load latency) ----
        int rowg[2][4];
        #pragma unroll
        for (int u = 0; u < 2; ++u)
            #pragma unroll
            for (int r = 0; r < 4; ++r) {
                int gr = row0 + 16 * u + quad * 4 + r;
                rowg[u][r] = (gr < NPTS) ? batch[gr] : -1;
            }
        int gf = batch[row0 < NPTS ? row0 : NPTS - 1];
        int rl = row0 + 31; if (rl > NPTS - 1) rl = NPTS - 1;
        int gl = batch[rl];
        // A-ext fragments: pos of this lane's rows in k-slots 0..2 (quad 0 only)
        bf16x8 aE[2];
        #pragma unroll
        for (int u = 0; u < 2; ++u) {
            bf16x8 a = (bf16x8){0, 0, 0, 0, 0, 0, 0, 0};
            int gp = row0 + 16 * u + mr; if (gp > NPTS - 1) gp = NPTS - 1;
            if (quad == 0) {
                a[0] = (__bf16)pos[gp * 3 + 0];
                a[1] = (__bf16)pos[gp * 3 + 1];
                a[2] = (__bf16)pos[gp * 3 + 2];
            }
            aE[u] = a;
        }

        // ---- A fragments ----
        bf16x8 afr[2][2];
        #pragma unroll
        for (int u = 0; u < 2; ++u)
            #pragma unroll
            for (int h = 0; h < 2; ++h) {
                f32x4 va = av[u][2 * h], vb = av[u][2 * h + 1];
                bf16x8 a;
                a[0] = (__bf16)va[0]; a[1] = (__bf16)va[1]; a[2] = (__bf16)va[2]; a[3] = (__bf16)va[3];
                a[4] = (__bf16)vb[0]; a[5] = (__bf16)vb[1]; a[6] = (__bf16)vb[2]; a[7] = (__bf16)vb[3];
                afr[u][h] = a;
            }

        // ---- GEMM1: x.W1a (K=64) + pos.W1e (K-ext, zero-padded), B from global ----
        f32x4 acc[2][8];
        #pragma unroll
        for (int u = 0; u < 2; ++u)
            #pragma unroll
            for (int t8 = 0; t8 < 8; ++t8) acc[u][t8] = (f32x4){0.f, 0.f, 0.f, 0.f};
        #pragma unroll
        for (int t8 = 0; t8 < 8; ++t8) {
            const u32x4* pbv = (const u32x4*)(W1aT + (t8 * 16 + mr) * 64 + quad * 8);
            bf16x8 bv0 = __builtin_bit_cast(bf16x8, pbv[0]);
            bf16x8 bv1 = __builtin_bit_cast(bf16x8, pbv[4]);
            bf16x8 bve = __builtin_bit_cast(bf16x8, *(const u32x4*)(W1eT + (t8 * 16 + mr) * 32 + quad * 8));
            #pragma unroll
            for (int u = 0; u < 2; ++u) {
                acc[u][t8] = __builtin_amdgcn_mfma_f32_16x16x32_bf16(afr[u][0], bv0, acc[u][t8], 0, 0, 0);
                acc[u][t8] = __builtin_amdgcn_mfma_f32_16x16x32_bf16(afr[u][1], bv1, acc[u][t8], 0, 0, 0);
                acc[u][t8] = __builtin_amdgcn_mfma_f32_16x16x32_bf16(aE[u],     bve, acc[u][t8], 0, 0, 0);
            }
        }

        // ---- epilogue1: h = relu(acc + cbias[g]) -> wave-private LDS stripe ----
        #pragma unroll
        for (int u = 0; u < 2; ++u)
            #pragma unroll
            for (int r = 0; r < 4; ++r) {
                int lrow = 16 * u + quad * 4 + r;
                int g = rowg[u][r]; int gc = g < 0 ? 0 : g;
                #pragma unroll
                for (int t8 = 0; t8 < 8; ++t8) {
                    float cbv = cbias[gc * 128 + t8 * 16 + mr];
                    float v = fmaxf(acc[u][t8][r] + cbv, 0.f);
                    hsb[lrow * 136 + t8 * 16 + mr] = (__bf16)v;
                }
            }
        // no barrier: GEMM2 reads only this wave's own stripe (same-wave RAW)

        // ---- GEMM2: h.W2, B from global ----
        f32x4 acc2[2][8];
        #pragma unroll
        for (int u = 0; u < 2; ++u)
            #pragma unroll
            for (int t8 = 0; t8 < 8; ++t8) acc2[u][t8] = (f32x4){0.f, 0.f, 0.f, 0.f};
        #pragma unroll
        for (int kk = 0; kk < 4; ++kk) {
            bf16x8 a2[2];
            #pragma unroll
            for (int u = 0; u < 2; ++u)
                a2[u] = __builtin_bit_cast(bf16x8, *(const u32x4*)(hss + (16 * u + mr) * 136 + kk * 32 + quad * 8));
            #pragma unroll
            for (int t8 = 0; t8 < 8; ++t8) {
                bf16x8 bv = __builtin_bit_cast(bf16x8, *(const u32x4*)(W2T + (t8 * 16 + mr) * 128 + kk * 32 + quad * 8));
                #pragma unroll
                for (int u = 0; u < 2; ++u)
                    acc2[u][t8] = __builtin_amdgcn_mfma_f32_16x16x32_bf16(a2[u], bv, acc2[u][t8], 0, 0, 0);
            }
        }

        // ---- epilogue2: per-graph column max -> global atomicMax (r1-proven) ----
        for (int g = gf; g <= gl; ++g) {
            #pragma unroll
            for (int t8 = 0; t8 < 8; ++t8) {
                float m = -INFINITY;
                #pragma unroll
                for (int u = 0; u < 2; ++u)
                    #pragma unroll
                    for (int r = 0; r < 4; ++r)
                        if (rowg[u][r] == g) m = fmaxf(m, acc2[u][t8][r]);
                m = fmaxf(m, __shfl_xor(m, 16));
                m = fmaxf(m, __shfl_xor(m, 32));
                if (quad == 0 && __builtin_bit_cast(unsigned, m) != 0xFF800000u)
                    atomicMax(&outacc[g * 128 + t8 * 16 + mr], mapf(m));
            }
        }
    }

    // ---- fused k_out: last block to finish converts outacc -> outf ----
    __threadfence();
    __syncthreads();
    if (tid == 0) sflag = atomicAdd(done, 1u);
    __syncthreads();
    if (sflag == (unsigned)(gridDim.x - 1)) {
        for (int i = tid; i < 8192; i += 512) {
            unsigned key = atomicMax(&outacc[i], 0u);   // device-scope read
            float v;
            if (key == 0u) {
                v = -300.f;   // diagnostic: never updated
            } else {
                unsigned bits = (key & 0x80000000u) ? (key & 0x7FFFFFFFu) : ~key;
                union { unsigned u; float f; } c; c.u = bits; v = c.f;
            }
            outf[i] = v + b2v[i & 127];
        }
    }
}

extern "C" void kernel_launch(void* const* d_in, const int* in_sizes, int n_in,
                              void* d_out, int out_size, void* d_ws, size_t ws_size,
                              hipStream_t stream) {
    const float* x   = (const float*)d_in[0];
    const float* pos = (const float*)d_in[1];
    const int*   bat = (const int*)d_in[2];
    const float* lfr = (const float*)d_in[3];
    const float* W1  = (const float*)d_in[4];
    const float* b1  = (const float*)d_in[5];
    const float* W2  = (const float*)d_in[6];
    const float* b2v = (const float*)d_in[7];
    float* outf = (float*)d_out;

    char* ws = (char*)d_ws;
    unsigned*       done   = (unsigned*)(ws + OFF_DONE);
    unsigned*       outacc = (unsigned*)(ws + OFF_OUTACC);
    float*          cbias  = (float*)(ws + OFF_CBIAS);
    unsigned short* W1aT   = (unsigned short*)(ws + OFF_W1AT);
    unsigned short* W2T    = (unsigned short*)(ws + OFF_W2T);
    unsigned short* W1eT   = (unsigned short*)(ws + OFF_W1ET);

    k_pre<<<64, 1024, 0, stream>>>(pos, bat, x, W1, b1, W2, lfr,
                                   W1aT, W2T, W1eT, outacc, done, cbias, outf);
    k_main<<<GRID2, 512, 0, stream>>>(x, pos, bat, W1aT, W2T, W1eT, cbias,
                                      outacc, done, b2v, outf);
}

// Round 7
// 320.845 us; speedup vs baseline: 1.5157x; 1.5157x over previous
//
#include <hip/hip_runtime.h>
#include <hip/hip_bf16.h>

#define NPTS 500000
#define NGR  64
#define TR   256
#define NT2  ((NPTS + TR - 1) / TR)   // 1954
#define GRID2 256

typedef __bf16 bf16x8 __attribute__((ext_vector_type(8)));
typedef float f32x4 __attribute__((ext_vector_type(4)));
typedef unsigned int u32x4 __attribute__((ext_vector_type(4)));

// ---- workspace layout (bytes), all 16B aligned ----
#define OFF_DONE   4096     // u32      : completion counter (k_out fused into k_main tail)
#define OFF_OUTACC 6144     // u32[8192]: order-preserving max accum
#define OFF_CBIAS  38912    // f32[8192]: per-graph GEMM1 bias row
#define OFF_W1PT   71680    // f32[512] : W1[128:131]^T padded [128][4] (plain)
#define OFF_W1AT   73728    // u16[8192] : bf16 W1[64:128]^T [n=128][k=64], XOR-swizzled
#define OFF_W2T    90112    // u16[16384]: bf16 W2^T [n=128][k=128], XOR-swizzled

// order-preserving float->u32 map (max over u32 == max over float)
__device__ __forceinline__ unsigned mapf(float f) {
    union { float f; unsigned u; } v; v.f = f;
    return ((int)v.u >= 0) ? (v.u | 0x80000000u) : ~v.u;
}

#define GLOAD_LDS16(g, l) __builtin_amdgcn_global_load_lds(                 \
    (__attribute__((address_space(1))) void*)(g),                           \
    (__attribute__((address_space(3))) void*)(l), 16, 0, 0)

// ---- fused pre-pass (one 1024-thread block per graph):
//      distributed prep (swizzled W transposes, outacc/done init) +
//      COM (fp64) + argmin (truncated key) + cbias. No atomics.
//      (r6-proven structure; prep writes the r1-proven swizzled W layout.) ----
__global__ __launch_bounds__(1024) void k_pre(
                      const float* __restrict__ pos,
                      const int* __restrict__ batch,
                      const float* __restrict__ x,
                      const float* __restrict__ W1,
                      const float* __restrict__ b1,
                      const float* __restrict__ W2,
                      const float* __restrict__ lfr,
                      unsigned short* __restrict__ W1aT,
                      unsigned short* __restrict__ W2T,
                      float* __restrict__ W1pT,
                      unsigned* __restrict__ outacc,
                      unsigned* __restrict__ done,
                      float* __restrict__ cbias,
                      float* __restrict__ outf) {
    __shared__ double sd[16][3];
    __shared__ unsigned long long sk[16];
    __shared__ double scom[3];
    __shared__ int sid;
    __shared__ float sposd[3];
    __shared__ float sp[4][128];
    __shared__ int sse[2];

    int g = blockIdx.x, t = threadIdx.x;
    int lane = t & 63, wv = t >> 6;   // wv 0..15

    // ---- distributed prep: 64*1024 = 65536 threads cover all items ----
    {
        int i = g * 1024 + t;
        if (i == 0) *done = 0u;
        if (i < 8192) {
            outacc[i] = 0u;
            int n = i >> 6, k = i & 63;
            unsigned short v = (unsigned short)(__builtin_bit_cast(unsigned, (float)(__bf16)W1[(64 + k) * 128 + n]) >> 16);
            W1aT[i ^ ((n & 7) << 3)] = v;
        } else if (i < 8192 + 16384) {
            int j = i - 8192; int n = j >> 7, k = j & 127;
            unsigned short v = (unsigned short)(__builtin_bit_cast(unsigned, (float)(__bf16)W2[k * 128 + n]) >> 16);
            W2T[j ^ ((n & 7) << 3)] = v;
        } else if (i < 8192 + 16384 + 512) {
            int j = i - 24576; int n = j >> 2, q = j & 3;
            W1pT[j] = (q < 3) ? W1[(128 + q) * 128 + n] : 0.f;
        }
    }

    // ---- own-range binary search (batch is sorted) ----
    if (t < 2) {
        int target = g + t;
        int lo = 0, hi = NPTS;
        while (lo < hi) {
            int mid = (lo + hi) >> 1;
            if (batch[mid] < target) lo = mid + 1; else hi = mid;
        }
        sse[t] = lo;
    }
    __syncthreads();
    int s = sse[0], e = sse[1];

    // pass 1: fp64 position sums
    double sx = 0.0, sy = 0.0, sz = 0.0;
    for (int i = s + t; i < e; i += 1024) {
        sx += (double)pos[i * 3 + 0];
        sy += (double)pos[i * 3 + 1];
        sz += (double)pos[i * 3 + 2];
    }
    #pragma unroll
    for (int m = 1; m < 64; m <<= 1) {
        sx += __shfl_xor(sx, m);
        sy += __shfl_xor(sy, m);
        sz += __shfl_xor(sz, m);
    }
    if (lane == 0) { sd[wv][0] = sx; sd[wv][1] = sy; sd[wv][2] = sz; }
    __syncthreads();
    if (t == 0) {
        double ax = 0.0, ay = 0.0, az = 0.0;
        for (int q = 0; q < 16; ++q) { ax += sd[q][0]; ay += sd[q][1]; az += sd[q][2]; }
        double cnt = (double)(e - s);
        double rc = 1.0 / (cnt > 1.0 ? cnt : 1.0);
        scom[0] = ax * rc; scom[1] = ay * rc; scom[2] = az * rc;
    }
    __syncthreads();
    double cx = scom[0], cy = scom[1], cz = scom[2];

    // pass 2: argmin of fp64 d2, key = (trunc d2-bits) | id
    unsigned long long key = ~0ULL;
    for (int i = s + t; i < e; i += 1024) {
        double dx = (double)pos[i * 3 + 0] - cx;
        double dy = (double)pos[i * 3 + 1] - cy;
        double dz = (double)pos[i * 3 + 2] - cz;
        double d2 = __builtin_fma(dx, dx, __builtin_fma(dy, dy, dz * dz));
        unsigned long long b = __builtin_bit_cast(unsigned long long, d2);
        unsigned long long k2 = (b & ~0xFFFFFULL) | (unsigned long long)i;
        key = k2 < key ? k2 : key;
    }
    #pragma unroll
    for (int m = 1; m < 64; m <<= 1) {
        unsigned long long o = __shfl_xor(key, m);
        key = o < key ? o : key;
    }
    if (lane == 0) sk[wv] = key;
    __syncthreads();
    if (t == 0) {
        unsigned long long k = sk[0];
        for (int q = 1; q < 16; ++q) if (sk[q] < k) k = sk[q];
        int id = (int)(k & 0xFFFFFULL);
        if (id > NPTS - 1) id = NPTS - 1;
        sid = id;
    }
    __syncthreads();
    int id = sid;

    if (t < 3) {
        float p = pos[id * 3 + t];
        sposd[t] = p;
        outf[8192 + g * 3 + t] = p;
    }
    if (t == 4) outf[8192 + 192 + g] = (float)batch[id];
    if (t < 9) outf[8192 + 256 + g * 9 + t] = lfr[id * 9 + t];

    // cbias: 4-way split over k, then ordered combine
    if (t < 512) {
        int c = t & 127, p = t >> 7;
        float part = 0.f;
        #pragma unroll
        for (int kq = 0; kq < 16; ++kq) {
            int k = p * 16 + kq;
            float xd = x[id * 64 + k];
            part += xd * (W1[k * 128 + c] - W1[(64 + k) * 128 + c]);
        }
        sp[p][c] = part;
    }
    __syncthreads();
    if (t < 128) {
        int c = t;
        float sv = b1[c] + sp[0][c] + sp[1][c] + sp[2][c] + sp[3][c];
        sv -= sposd[0] * W1[128 * 128 + c] + sposd[1] * W1[129 * 128 + c] + sposd[2] * W1[130 * 128 + c];
        cbias[g * 128 + c] = sv;
    }
}

// ---- main: ROUND-1 KERNEL VERBATIM (measured 90.4 us, 108 VGPR, no spill):
//      8 waves x 32 rows, (512,2); W staged once to LDS (XOR-swizzled,
//      conflict-free); A direct global->VGPR; h in wave-private LDS stripe;
//      zero barriers in the loop. Only addition: r4/r6-proven completion-
//      counter tail (runs after the loop; register-neutral).
//      DO NOT source B-fragments from global here: global B-loads get hoisted
//      (long live ranges) and push demand past the 128-VGPR (512,2) cap ->
//      scratch spill (r6: FETCH 403MB/WRITE 185MB). LDS-sourced B is what
//      keeps this kernel at 108 VGPRs. ----
__global__ __launch_bounds__(512, 2) void k_main(
    const float* __restrict__ x,
    const float* __restrict__ pos,
    const int* __restrict__ batch,
    const unsigned short* __restrict__ W1aT,
    const unsigned short* __restrict__ W2T,
    const float* __restrict__ W1pT,
    const float* __restrict__ cbias,
    unsigned* __restrict__ outacc,
    unsigned* __restrict__ done,
    const float* __restrict__ b2v,
    float* __restrict__ outf)
{
    // [0,16384): W1aT swizzled bf16 [128][64]
    // [16384,49152): W2T swizzled bf16 [128][128]
    // [49152,118784): h stripes: 8 waves x [32][136] bf16 (8704 B each)
    __shared__ alignas(16) unsigned char smem[118784];
    __shared__ unsigned sflag;

    const int tid  = threadIdx.x;        // 0..511
    const int w    = tid >> 6;           // 0..7
    const int lane = tid & 63;
    const int quad = lane >> 4;
    const int mr   = lane & 15;

    // stage W once (linear copy; global layout is pre-swizzled)
    #pragma unroll
    for (int i = 0; i < 2; ++i)
        GLOAD_LDS16((const char*)W1aT + (i * 512 + tid) * 16,
                    (char*)smem + (i * 512 + tid) * 16);
    #pragma unroll
    for (int i = 0; i < 4; ++i)
        GLOAD_LDS16((const char*)W2T + (i * 512 + tid) * 16,
                    (char*)smem + 16384 + (i * 512 + tid) * 16);

    // tile-invariant: B-ext fragments for pos.W1p K-extension
    bf16x8 bfrE[8];
    #pragma unroll
    for (int t8 = 0; t8 < 8; ++t8) {
        f32x4 wp = *(const f32x4*)(W1pT + (t8 * 16 + mr) * 4);
        bf16x8 e = (bf16x8){0, 0, 0, 0, 0, 0, 0, 0};
        if (quad == 0) { e[0] = (__bf16)wp[0]; e[1] = (__bf16)wp[1]; e[2] = (__bf16)wp[2]; }
        bfrE[t8] = e;
    }

    __syncthreads();   // W staged; the only block-wide barrier before the tail

    const unsigned short* sW1 = (const unsigned short*)smem;
    const unsigned short* sW2 = (const unsigned short*)(smem + 16384);
    __bf16* hsb = (__bf16*)(smem + 49152) + w * 4352;   // [32][136]
    const unsigned short* hss = (const unsigned short*)hsb;

    for (int t = blockIdx.x; t < NT2; t += GRID2) {
        const int row0 = t * TR + 32 * w;   // this wave's 32 global rows

        // ---- A loads, direct global (issued first, 8x dwordx4) ----
        f32x4 av[2][4];
        #pragma unroll
        for (int u = 0; u < 2; ++u) {
            int gr2 = row0 + 16 * u + mr; if (gr2 > NPTS - 1) gr2 = NPTS - 1;
            const float* xp = x + (size_t)gr2 * 64 + quad * 8;
            av[u][0] = *(const f32x4*)(xp);
            av[u][1] = *(const f32x4*)(xp + 4);
            av[u][2] = *(const f32x4*)(xp + 32);
            av[u][3] = *(const f32x4*)(xp + 36);
        }

        // ---- per-tile meta (overlaps A-load latency) ----
        int rowg[2][4]; bool rowv[2][4];
        #pragma unroll
        for (int u = 0; u < 2; ++u)
            #pragma unroll
            for (int r = 0; r < 4; ++r) {
                int gr = row0 + 16 * u + quad * 4 + r;
                rowv[u][r] = (gr < NPTS);
                rowg[u][r] = batch[gr < NPTS ? gr : NPTS - 1];
            }
        int gf = batch[row0 < NPTS ? row0 : NPTS - 1];
        int rl = row0 + 31; if (rl > NPTS - 1) rl = NPTS - 1;
        int gl = batch[rl];
        float cb0[8];
        #pragma unroll
        for (int t8 = 0; t8 < 8; ++t8) cb0[t8] = cbias[gf * 128 + t8 * 16 + mr];
        float pE[2][3];
        #pragma unroll
        for (int u = 0; u < 2; ++u) {
            int gp = row0 + 16 * u + mr; if (gp > NPTS - 1) gp = NPTS - 1;
            pE[u][0] = pos[gp * 3 + 0];
            pE[u][1] = pos[gp * 3 + 1];
            pE[u][2] = pos[gp * 3 + 2];
        }

        // ---- A fragments ----
        bf16x8 afr[2][2];
        #pragma unroll
        for (int u = 0; u < 2; ++u)
            #pragma unroll
            for (int h = 0; h < 2; ++h) {
                f32x4 va = av[u][2 * h], vb = av[u][2 * h + 1];
                bf16x8 a;
                a[0] = (__bf16)va[0]; a[1] = (__bf16)va[1]; a[2] = (__bf16)va[2]; a[3] = (__bf16)va[3];
                a[4] = (__bf16)vb[0]; a[5] = (__bf16)vb[1]; a[6] = (__bf16)vb[2]; a[7] = (__bf16)vb[3];
                afr[u][h] = a;
            }

        // ---- GEMM1 (B from swizzled LDS) + pos.W1p K-extension ----
        f32x4 acc[2][8];
        #pragma unroll
        for (int u = 0; u < 2; ++u)
            #pragma unroll
            for (int t8 = 0; t8 < 8; ++t8) acc[u][t8] = (f32x4){0.f, 0.f, 0.f, 0.f};
        #pragma unroll
        for (int t8 = 0; t8 < 8; ++t8) {
            int n = t8 * 16 + mr;
            int sw = (n & 7) << 3;
            bf16x8 bv0 = __builtin_bit_cast(bf16x8, *(const u32x4*)(sW1 + ((n * 64 + quad * 8) ^ sw)));
            bf16x8 bv1 = __builtin_bit_cast(bf16x8, *(const u32x4*)(sW1 + ((n * 64 + 32 + quad * 8) ^ sw)));
            #pragma unroll
            for (int u = 0; u < 2; ++u) {
                acc[u][t8] = __builtin_amdgcn_mfma_f32_16x16x32_bf16(afr[u][0], bv0, acc[u][t8], 0, 0, 0);
                acc[u][t8] = __builtin_amdgcn_mfma_f32_16x16x32_bf16(afr[u][1], bv1, acc[u][t8], 0, 0, 0);
            }
        }
        bf16x8 aE[2];
        #pragma unroll
        for (int u = 0; u < 2; ++u) {
            bf16x8 a = (bf16x8){0, 0, 0, 0, 0, 0, 0, 0};
            if (quad == 0) { a[0] = (__bf16)pE[u][0]; a[1] = (__bf16)pE[u][1]; a[2] = (__bf16)pE[u][2]; }
            aE[u] = a;
        }
        #pragma unroll
        for (int t8 = 0; t8 < 8; ++t8)
            #pragma unroll
            for (int u = 0; u < 2; ++u)
                acc[u][t8] = __builtin_amdgcn_mfma_f32_16x16x32_bf16(aE[u], bfrE[t8], acc[u][t8], 0, 0, 0);

        // ---- epilogue1: h = relu(acc + cbias[g]) -> wave-private LDS stripe ----
        #pragma unroll
        for (int u = 0; u < 2; ++u)
            #pragma unroll
            for (int r = 0; r < 4; ++r) {
                int lrow = 16 * u + quad * 4 + r;
                int g = rowg[u][r];
                bool odd = (g != gf);
                #pragma unroll
                for (int t8 = 0; t8 < 8; ++t8) {
                    float cbv = cb0[t8];
                    if (odd) cbv = cbias[g * 128 + t8 * 16 + mr];
                    float v = fmaxf(acc[u][t8][r] + cbv, 0.f);
                    hsb[lrow * 136 + t8 * 16 + mr] = (__bf16)v;
                }
            }
        // no barrier: GEMM2 reads only this wave's own stripe (same-wave RAW)

        // ---- GEMM2 (A from own h stripe, B from swizzled LDS) ----
        f32x4 acc2[2][8];
        #pragma unroll
        for (int u = 0; u < 2; ++u)
            #pragma unroll
            for (int t8 = 0; t8 < 8; ++t8) acc2[u][t8] = (f32x4){0.f, 0.f, 0.f, 0.f};
        #pragma unroll
        for (int kk = 0; kk < 4; ++kk) {
            bf16x8 a2[2];
            #pragma unroll
            for (int u = 0; u < 2; ++u)
                a2[u] = __builtin_bit_cast(bf16x8, *(const u32x4*)(hss + (16 * u + mr) * 136 + kk * 32 + quad * 8));
            #pragma unroll
            for (int t8 = 0; t8 < 8; ++t8) {
                int n = t8 * 16 + mr;
                bf16x8 bv = __builtin_bit_cast(bf16x8, *(const u32x4*)(sW2 + ((n * 128 + kk * 32 + quad * 8) ^ ((n & 7) << 3))));
                #pragma unroll
                for (int u = 0; u < 2; ++u)
                    acc2[u][t8] = __builtin_amdgcn_mfma_f32_16x16x32_bf16(a2[u], bv, acc2[u][t8], 0, 0, 0);
            }
        }

        // ---- epilogue2: per-graph column max -> global atomicMax ----
        for (int g = gf; g <= gl; ++g) {
            #pragma unroll
            for (int t8 = 0; t8 < 8; ++t8) {
                float m = -INFINITY;
                #pragma unroll
                for (int u = 0; u < 2; ++u)
                    #pragma unroll
                    for (int r = 0; r < 4; ++r)
                        if (rowv[u][r] && rowg[u][r] == g) m = fmaxf(m, acc2[u][t8][r]);
                m = fmaxf(m, __shfl_xor(m, 16));
                m = fmaxf(m, __shfl_xor(m, 32));
                unsigned mb = __builtin_bit_cast(unsigned, m);
                if (quad == 0 && mb != 0xFF800000u)
                    atomicMax(&outacc[g * 128 + t8 * 16 + mr], mapf(m));
            }
        }
    }

    // ---- fused k_out: last block to finish converts outacc -> outf ----
    __threadfence();
    __syncthreads();
    if (tid == 0) sflag = atomicAdd(done, 1u);
    __syncthreads();
    if (sflag == (unsigned)(gridDim.x - 1)) {
        for (int i = tid; i < 8192; i += 512) {
            unsigned key = atomicMax(&outacc[i], 0u);   // device-scope read
            float v;
            if (key == 0u) {
                v = -300.f;   // diagnostic: never updated
            } else {
                unsigned bits = (key & 0x80000000u) ? (key & 0x7FFFFFFFu) : ~key;
                union { unsigned u; float f; } c; c.u = bits; v = c.f;
            }
            outf[i] = v + b2v[i & 127];
        }
    }
}

extern "C" void kernel_launch(void* const* d_in, const int* in_sizes, int n_in,
                              void* d_out, int out_size, void* d_ws, size_t ws_size,
                              hipStream_t stream) {
    const float* x   = (const float*)d_in[0];
    const float* pos = (const float*)d_in[1];
    const int*   bat = (const int*)d_in[2];
    const float* lfr = (const float*)d_in[3];
    const float* W1  = (const float*)d_in[4];
    const float* b1  = (const float*)d_in[5];
    const float* W2  = (const float*)d_in[6];
    const float* b2v = (const float*)d_in[7];
    float* outf = (float*)d_out;

    char* ws = (char*)d_ws;
    unsigned*       done   = (unsigned*)(ws + OFF_DONE);
    unsigned*       outacc = (unsigned*)(ws + OFF_OUTACC);
    float*          cbias  = (float*)(ws + OFF_CBIAS);
    float*          W1pT   = (float*)(ws + OFF_W1PT);
    unsigned short* W1aT   = (unsigned short*)(ws + OFF_W1AT);
    unsigned short* W2T    = (unsigned short*)(ws + OFF_W2T);

    k_pre<<<64, 1024, 0, stream>>>(pos, bat, x, W1, b1, W2, lfr,
                                   W1aT, W2T, W1pT, outacc, done, cbias, outf);
    k_main<<<GRID2, 512, 0, stream>>>(x, pos, bat, W1aT, W2T, W1pT, cbias,
                                      outacc, done, b2v, outf);
}